// Round 17
// baseline (407.596 us; speedup 1.0000x reference)
//
#include <hip/hip_runtime.h>
#include <hip/hip_fp16.h>
#include <math.h>

#define NN 25000
#define NE 400000
#define HD 64
#define EMBD 8
#define NG 16
#define NC 10
#define SCAN_NB 98   // ceil(NN/256)
#define NWE 16384
#define NSL 16       // stat shadow slices (atomic-contention sharding)
#define STATS_F (NSL * 64 + NSL * 64 + NSL * 1024)   // sumsN + sumsqN + XgN

typedef _Float16 f16x8 __attribute__((ext_vector_type(8)));
typedef float f32x4 __attribute__((ext_vector_type(4)));

// ---------------------------------------------------------------------------
// Sort phase: dst-CSR (edge structure is layer-invariant).
// ---------------------------------------------------------------------------
__global__ __launch_bounds__(256) void hist_k(const int* __restrict__ dst, int* cnt) {
    int e = blockIdx.x * 256 + threadIdx.x;
    if (e < NE) atomicAdd(&cnt[dst[e]], 1);
}

__global__ __launch_bounds__(256) void scan_part_k(const int* __restrict__ cnt, int* bsum) {
    __shared__ int sh[256];
    int tx = threadIdx.x;
    int i = blockIdx.x * 256 + tx;
    sh[tx] = (i < NN) ? cnt[i] : 0;
    __syncthreads();
    for (int off = 128; off > 0; off >>= 1) {
        if (tx < off) sh[tx] += sh[tx + off];
        __syncthreads();
    }
    if (tx == 0) bsum[blockIdx.x] = sh[0];
}

// scan of block sums + gcnt[g] via binary search on sorted gids (no atomics:
// sorted ids caused 175us same-bin atomic serialization in R8).
__global__ __launch_bounds__(128) void scan_mid_k(const int* __restrict__ bsum,
        int* boff, int* dstoff, const int* __restrict__ gids, int* gcnt) {
    __shared__ int sh[128];
    int tx = threadIdx.x;
    int v = (tx < SCAN_NB) ? bsum[tx] : 0;
    sh[tx] = v;
    __syncthreads();
    for (int off = 1; off < 128; off <<= 1) {
        int t = (tx >= off) ? sh[tx - off] : 0;
        __syncthreads();
        sh[tx] += t;
        __syncthreads();
    }
    if (tx < SCAN_NB) boff[tx] = sh[tx] - v;
    if (tx == 0) dstoff[NN] = NE;
    if (tx < NG) {
        int lo = 0, hi = NN;
        while (lo < hi) { int m = (lo + hi) >> 1; if (gids[m] < tx) lo = m + 1; else hi = m; }
        int a = lo;
        lo = 0; hi = NN;
        while (lo < hi) { int m = (lo + hi) >> 1; if (gids[m] < tx + 1) lo = m + 1; else hi = m; }
        gcnt[tx] = lo - a;
    }
}

__global__ __launch_bounds__(256) void scan_final_k(const int* __restrict__ cnt,
        const int* __restrict__ boff, int* dstoff, int* cur) {
    __shared__ int sh[256];
    int tx = threadIdx.x;
    int i = blockIdx.x * 256 + tx;
    int v = (i < NN) ? cnt[i] : 0;
    sh[tx] = v;
    __syncthreads();
    for (int off = 1; off < 256; off <<= 1) {
        int t = (tx >= off) ? sh[tx - off] : 0;
        __syncthreads();
        sh[tx] += t;
        __syncthreads();
    }
    int excl = boff[blockIdx.x] + sh[tx] - v;
    if (i < NN) { dstoff[i] = excl; cur[i] = excl; }
}

// once: per-wave node ranges for edge_E (layer-invariant).
__global__ __launch_bounds__(256) void wave_range_k(const int* __restrict__ dstoff,
        int* __restrict__ wrange) {
    int w = blockIdx.x * 256 + threadIdx.x;
    if (w > NWE) return;
    if (w == NWE) { wrange[w] = NN; return; }
    long long t0 = (long long)w * NE / NWE;
    int lo = 0, hi = NN;
    while (lo < hi) { int m = (lo + hi) >> 1; if (dstoff[m] < t0) lo = m + 1; else hi = m; }
    wrange[w] = lo;
}

// scatter: place src at dst-sorted slot AND precompute normalized direction.
__global__ __launch_bounds__(256) void scatter_k(const int* __restrict__ src,
        const int* __restrict__ dst, const float* __restrict__ c,
        int* cur, int* __restrict__ src_d, float* __restrict__ dnorm_d) {
    int e = blockIdx.x * 256 + threadIdx.x;
    if (e >= NE) return;
    int s = src[e], t = dst[e];
    int pd = atomicAdd(&cur[t], 1);
    src_d[pd] = s;
    float4 sa = *(const float4*)(c + (size_t)s * 8);
    float4 sb = *(const float4*)(c + (size_t)s * 8 + 4);
    float4 na = *(const float4*)(c + (size_t)t * 8);
    float4 nb = *(const float4*)(c + (size_t)t * 8 + 4);
    float d0 = sa.x - na.x, d1 = sa.y - na.y, d2 = sa.z - na.z, d3 = sa.w - na.w;
    float d4 = sb.x - nb.x, d5 = sb.y - nb.y, d6 = sb.z - nb.z, d7 = sb.w - nb.w;
    float nn2 = d0*d0 + d1*d1 + d2*d2 + d3*d3 + d4*d4 + d5*d5 + d6*d6 + d7*d7;
    float inv = 1.f / fmaxf(sqrtf(nn2), 1e-12f);
    *(float4*)(dnorm_d + (size_t)pd * 8)     = make_float4(d0*inv, d1*inv, d2*inv, d3*inv);
    *(float4*)(dnorm_d + (size_t)pd * 8 + 4) = make_float4(d4*inv, d5*inv, d6*inv, d7*inv);
}

// one-time fp16 shadow of the layer-0 features
__global__ __launch_bounds__(256) void cast_h16_k(const float* __restrict__ h,
        __half* __restrict__ h16) {
    int i4 = blockIdx.x * 256 + threadIdx.x;
    if (i4 >= NN * 16) return;
    float4 v = *(const float4*)(h + (size_t)i4 * 4);
    __half2 lo = __floats2half2_rn(v.x, v.y);
    __half2 hi = __floats2half2_rn(v.z, v.w);
    *(__half2*)(h16 + (size_t)i4 * 4)     = lo;
    *(__half2*)(h16 + (size_t)i4 * 4 + 2) = hi;
}

// one-time: cast+permute all 3 W to fp16 Wt[l][k][q'] with q' = j*8+i.
__global__ __launch_bounds__(256) void cast_wt_k(const float* __restrict__ W0,
        const float* __restrict__ W1, const float* __restrict__ W2,
        __half* __restrict__ Wt) {
    int i = blockIdx.x * 256 + threadIdx.x;   // 3*64*512
    if (i >= 3 * 64 * 512) return;
    int l = i >> 15;
    int rem = i & 32767;
    int k = rem >> 9;         // 0..63
    int qp = rem & 511;       // q' = j*8+i
    int ii = qp & 7;
    int jj = qp >> 3;
    const float* W = (l == 0) ? W0 : ((l == 1) ? W1 : W2);
    Wt[i] = __float2half_rn(W[(size_t)(ii * 64 + jj) * 64 + k]);
}

// ---------------------------------------------------------------------------
// K1: E16[t, q'=j*8+i] = sum_{e->t} dnorm[e,i] * h[src_e, j]
// The 8 h-row reads per batch are UNCONDITIONAL (index clamped) so the
// compiler can issue all 8 before one waitcnt — with the old `if (j<m)`
// guards it allocated only 28 VGPRs and serialized every load (why R7/R11/R8
// ILP attempts were all flat).
// ---------------------------------------------------------------------------
__global__ __launch_bounds__(256) void edge_E_k(const int* __restrict__ src_d,
        const int* __restrict__ dstoff, const int* __restrict__ wrange,
        const float* __restrict__ dnorm_d,
        const __half* __restrict__ h16, __half* __restrict__ E16,
        float* __restrict__ stats_zero) {
    // zero the sharded stats block (sumsN+sumsqN+XgN) cooperatively
    int zstride = gridDim.x * 256;
    for (int t = blockIdx.x * 256 + threadIdx.x; t < STATS_F; t += zstride)
        stats_zero[t] = 0.f;
    int gid  = blockIdx.x * 256 + threadIdx.x;
    int w    = gid >> 6;
    int lane = threadIdx.x & 63;
    int nlo = wrange[w];
    int nhi = wrange[w + 1];

    int wbase = -1000000;
    int sidx = 0;
    for (int n = nlo; n < nhi; n++) {
        float e0=0,e1=0,e2=0,e3=0,e4=0,e5=0,e6=0,e7=0;
        int p0 = dstoff[n], p1 = dstoff[n + 1];
        int p = p0;
        while (p < p1) {
            if (p - wbase > 56) {   // guarantee 8 indices in the 64-wide window
                wbase = p;
                int ld = wbase + lane;
                if (ld > NE - 1) ld = NE - 1;
                sidx = src_d[ld];
            }
            int m = p1 - p; if (m > 8) m = 8;
            int pj[8]; int sj[8]; __half hj[8];
#pragma unroll
            for (int j = 0; j < 8; j++) {
                int q = p + j; if (q > p1 - 1) q = p1 - 1;   // clamp, wave-uniform
                pj[j] = q;
                sj[j] = __shfl(sidx, q - wbase);
            }
            // 8 independent row-reads, no guard -> all in flight before waitcnt
#pragma unroll
            for (int j = 0; j < 8; j++)
                hj[j] = h16[(size_t)sj[j] * 64 + lane];
#pragma unroll
            for (int j = 0; j < 8; j++)
                if (j < m) {
                    float4 dA = *(const float4*)(dnorm_d + (size_t)pj[j] * 8);
                    float4 dB = *(const float4*)(dnorm_d + (size_t)pj[j] * 8 + 4);
                    float hv = __half2float(hj[j]);
                    e0 = fmaf(dA.x, hv, e0); e1 = fmaf(dA.y, hv, e1);
                    e2 = fmaf(dA.z, hv, e2); e3 = fmaf(dA.w, hv, e3);
                    e4 = fmaf(dB.x, hv, e4); e5 = fmaf(dB.y, hv, e5);
                    e6 = fmaf(dB.z, hv, e6); e7 = fmaf(dB.w, hv, e7);
                }
            p += m;
        }
        float4 pack;
        ((__half2*)&pack)[0] = __floats2half2_rn(e0, e1);
        ((__half2*)&pack)[1] = __floats2half2_rn(e2, e3);
        ((__half2*)&pack)[2] = __floats2half2_rn(e4, e5);
        ((__half2*)&pack)[3] = __floats2half2_rn(e6, e7);
        *(float4*)(E16 + (size_t)n * 512 + lane * 8) = pack;
    }
}

// ---------------------------------------------------------------------------
// K2 (MFMA): agg[n,k] = sum_q' E16[n,q'] * Wt16[k,q'], fp32 accumulate.
// Stats go to shadow slice (blockIdx & 15).
// ---------------------------------------------------------------------------
__global__ __launch_bounds__(256) void gemm_mfma_k(const __half* __restrict__ E16,
        const __half* __restrict__ Wt16, const int* __restrict__ gids,
        float* __restrict__ agg, float* __restrict__ sumsN,
        float* __restrict__ sumsqN, float* __restrict__ XgN) {
    __shared__ float pl[NG * 64];
    __shared__ float s1[64], s2[64];
    __shared__ int gsh[16];
    int tx = threadIdx.x;
    int wave = tx >> 6, lane = tx & 63;
    int n0 = blockIdx.x * 16;
    int c0 = wave * 16;
    int slice = blockIdx.x & (NSL - 1);
    for (int t = tx; t < NG * 64; t += 256) pl[t] = 0.f;
    if (tx < 64) { s1[tx] = 0.f; s2[tx] = 0.f; }
    if (tx < 16) gsh[tx] = gids[min(n0 + tx, NN - 1)];
    __syncthreads();

    int quad = lane >> 4;
    int lcol = lane & 15;
    int ar = n0 + lcol; if (ar > NN - 1) ar = NN - 1;
    const f16x8* pa = (const f16x8*)(E16 + (size_t)ar * 512 + quad * 8);
    const f16x8* pb = (const f16x8*)(Wt16 + (size_t)(c0 + lcol) * 512 + quad * 8);
    f32x4 acc = {0.f, 0.f, 0.f, 0.f};
#pragma unroll
    for (int kc = 0; kc < 16; kc++) {
        f16x8 a = pa[kc * 4];
        f16x8 b = pb[kc * 4];
        acc = __builtin_amdgcn_mfma_f32_16x16x32_f16(a, b, acc, 0, 0, 0);
    }

    int colg = c0 + lcol;
    float s1l = 0.f, s2l = 0.f;
#pragma unroll
    for (int r = 0; r < 4; r++) {
        int nrow = quad * 4 + r;
        int n = n0 + nrow;
        if (n < NN) {
            float v = acc[r];
            agg[(size_t)n * 64 + colg] = v;
            float x = fmaxf(v, 0.f);
            s1l += x; s2l += x * x;
            atomicAdd(&pl[gsh[nrow] * 64 + colg], x);
        }
    }
    atomicAdd(&s1[colg], s1l);
    atomicAdd(&s2[colg], s2l);
    __syncthreads();
    if (tx < 64) {
        atomicAdd(&sumsN[slice * 64 + tx], s1[tx]);
        atomicAdd(&sumsqN[slice * 64 + tx], s2[tx]);
    }
    for (int t = tx; t < NG * 64; t += 256) {
        float v = pl[t];
        if (v != 0.f) atomicAdd(&XgN[slice * 1024 + t], v);
    }
}

// ---------------------------------------------------------------------------
// Classifier via pooled-BN identity; stats summed over NSL shadow slices.
// ---------------------------------------------------------------------------
__device__ __forceinline__ void classifier_body(int tx,
        const float* __restrict__ sumsN, const float* __restrict__ sumsqN,
        const float* __restrict__ XgN, const int* __restrict__ gcnt,
        float* __restrict__ Pold,
        const float* __restrict__ gamma, const float* __restrict__ beta,
        const float* __restrict__ cW1, const float* __restrict__ cb1,
        const float* __restrict__ cg1, const float* __restrict__ cbt1,
        const float* __restrict__ cW2, const float* __restrict__ cb2,
        float* __restrict__ logits, int sc) {
    __shared__ float Pn[NG * 64];
    __shared__ float H1s[NG * 32];
    __shared__ float cmu[32], crs[32];
    for (int t = tx; t < NG * 64; t += 256) {
        int g = t >> 6, k = t & 63;
        float sk = 0.f, sq = 0.f, xg = 0.f;
#pragma unroll
        for (int s = 0; s < NSL; s++) {
            sk += sumsN[s * 64 + k];
            sq += sumsqN[s * 64 + k];
            xg += XgN[s * 1024 + t];
        }
        float mean = sk * (1.f / NN);
        float var  = sq * (1.f / NN) - mean * mean;
        float r = rsqrtf(var + 1e-5f);
        float cg = (float)gcnt[g];
        float v = gamma[k] * r * (xg - cg * mean) + cg * beta[k];
        if (sc) v += Pold[t];
        Pn[t] = v;
        Pold[t] = v;
    }
    __syncthreads();
    for (int t = tx; t < NG * 32; t += 256) {
        int g = t >> 5, c = t & 31;
        float acc = cb1[c];
#pragma unroll 16
        for (int j = 0; j < 64; j++) acc = fmaf(Pn[g * 64 + j], cW1[j * 32 + c], acc);
        H1s[t] = acc;
    }
    __syncthreads();
    if (tx < 32) {
        float mu = 0.f;
#pragma unroll
        for (int g2 = 0; g2 < NG; g2++) mu += H1s[g2 * 32 + tx];
        mu *= (1.f / NG);
        float v = 0.f;
#pragma unroll
        for (int g2 = 0; g2 < NG; g2++) {
            float d = H1s[g2 * 32 + tx] - mu;
            v += d * d;
        }
        v *= (1.f / NG);
        cmu[tx] = mu;
        crs[tx] = rsqrtf(v + 1e-5f);
    }
    __syncthreads();
    for (int t = tx; t < NG * 32; t += 256) {
        int c = t & 31;
        H1s[t] = fmaxf(cg1[c] * (H1s[t] - cmu[c]) * crs[c] + cbt1[c], 0.f);
    }
    __syncthreads();
    if (tx < NG * NC) {
        int g = tx / NC, cls = tx % NC;
        float a2 = cb2[cls];
#pragma unroll
        for (int j = 0; j < 32; j++) a2 = fmaf(H1s[g * 32 + j], cW2[j * NC + cls], a2);
        logits[tx] += a2;
    }
}

// ---------------------------------------------------------------------------
// K4: BN apply + shortcut -> h_new (fp32) + fp16 shadow; float4 I/O;
// block 0 also runs the classifier.
// ---------------------------------------------------------------------------
__global__ __launch_bounds__(256) void bn_apply_k(const float* __restrict__ agg,
        const float* __restrict__ h_old, const float* __restrict__ sumsN,
        const float* __restrict__ sumsqN, const float* __restrict__ gamma,
        const float* __restrict__ beta, float* __restrict__ h_new,
        __half* __restrict__ h16_out, int shortcut,
        const float* __restrict__ XgN, const int* __restrict__ gcnt,
        float* __restrict__ Pold,
        const float* __restrict__ cW1, const float* __restrict__ cb1,
        const float* __restrict__ cg1, const float* __restrict__ cbt1,
        const float* __restrict__ cW2, const float* __restrict__ cb2,
        float* __restrict__ logits) {
    int tx = threadIdx.x;
    int col0 = (tx & 15) * 4;
    float mean[4], rstd[4], gv[4], bv[4];
#pragma unroll
    for (int cc = 0; cc < 4; cc++) {
        int k = col0 + cc;
        float sk = 0.f, sq = 0.f;
#pragma unroll
        for (int s = 0; s < NSL; s++) {
            sk += sumsN[s * 64 + k];
            sq += sumsqN[s * 64 + k];
        }
        float mu = sk * (1.f / NN);
        float var = sq * (1.f / NN) - mu * mu;
        mean[cc] = mu;
        rstd[cc] = rsqrtf(var + 1e-5f);
        gv[cc] = gamma[k];
        bv[cc] = beta[k];
    }
    int row = blockIdx.x * 16 + (tx >> 4);
    int rstride = gridDim.x * 16;
    for (int n = row; n < NN; n += rstride) {
        float4 x4 = *(const float4*)(agg + (size_t)n * 64 + col0);
        float y[4] = {x4.x, x4.y, x4.z, x4.w};
#pragma unroll
        for (int cc = 0; cc < 4; cc++) {
            float x = fmaxf(y[cc], 0.f);
            y[cc] = gv[cc] * (x - mean[cc]) * rstd[cc] + bv[cc];
        }
        if (shortcut) {
            float4 h4 = *(const float4*)(h_old + (size_t)n * 64 + col0);
            y[0] += h4.x; y[1] += h4.y; y[2] += h4.z; y[3] += h4.w;
        }
        *(float4*)(h_new + (size_t)n * 64 + col0) = make_float4(y[0], y[1], y[2], y[3]);
        float2 pk;
        ((__half2*)&pk)[0] = __floats2half2_rn(y[0], y[1]);
        ((__half2*)&pk)[1] = __floats2half2_rn(y[2], y[3]);
        *(float2*)(h16_out + (size_t)n * 64 + col0) = pk;
    }
    if (blockIdx.x == 0)
        classifier_body(tx, sumsN, sumsqN, XgN, gcnt, Pold, gamma, beta,
                        cW1, cb1, cg1, cbt1, cW2, cb2, logits, shortcut);
}

// Layer 2: h_new never consumed -> classifier only (1 block).
__global__ __launch_bounds__(256) void classifier_only_k(
        const float* __restrict__ sumsN, const float* __restrict__ sumsqN,
        const float* __restrict__ XgN, const int* __restrict__ gcnt,
        float* __restrict__ Pold,
        const float* __restrict__ gamma, const float* __restrict__ beta,
        const float* __restrict__ cW1, const float* __restrict__ cb1,
        const float* __restrict__ cg1, const float* __restrict__ cbt1,
        const float* __restrict__ cW2, const float* __restrict__ cb2,
        float* __restrict__ logits) {
    classifier_body(threadIdx.x, sumsN, sumsqN, XgN, gcnt, Pold, gamma, beta,
                    cW1, cb1, cg1, cbt1, cW2, cb2, logits, 1);
}

// ---------------------------------------------------------------------------
extern "C" void kernel_launch(void* const* d_in, const int* in_sizes, int n_in,
                              void* d_out, int out_size, void* d_ws, size_t ws_size,
                              hipStream_t stream) {
    const float* feature = (const float*)d_in[0];
    const float* cemb    = (const float*)d_in[1];
    const int*   src     = (const int*)d_in[2];
    const int*   dst     = (const int*)d_in[3];
    const int*   gids    = (const int*)d_in[4];
    const float* W[3]    = {(const float*)d_in[5], (const float*)d_in[6], (const float*)d_in[7]};
    const float* gam[3]  = {(const float*)d_in[8], (const float*)d_in[10], (const float*)d_in[12]};
    const float* bet[3]  = {(const float*)d_in[9], (const float*)d_in[11], (const float*)d_in[13]};
    const float* cW1  = (const float*)d_in[14];
    const float* cb1  = (const float*)d_in[15];
    const float* cg1  = (const float*)d_in[16];
    const float* cbt1 = (const float*)d_in[17];
    const float* cW2  = (const float*)d_in[18];
    const float* cb2  = (const float*)d_in[19];
    float* out = (float*)d_out;

    // workspace layout (4-byte units)
    float* ws      = (float*)d_ws;
    __half* E16    = (__half*)ws;                  // NN*512 halfs = 6.4M floats
    float* dnorm_d = ws + (size_t)NN * 256;        // NE*8 = 3.2M
    float* bufX    = dnorm_d + (size_t)NE * 8;     // NN*64
    float* bufY    = bufX + (size_t)NN * 64;       // NN*64
    float* sumsN   = bufY + (size_t)NN * 64;       // NSL*64   } contiguous,
    float* sumsqN  = sumsN + NSL * 64;             // NSL*64   } zeroed by edge_E
    float* XgN     = sumsqN + NSL * 64;            // NSL*1024 }
    float* Pold    = sumsN + STATS_F;              // 1024 (persists across layers)
    int*   cnt     = (int*)(Pold + 1024);          // NN
    int*   gcnt    = cnt + NN;                     // 16
    int*   cur     = gcnt + 16;                    // NN
    int*   dstoff  = cur + NN;                     // NN+1 (pad +8)
    int*   bsum    = dstoff + NN + 8;              // 128
    int*   boff    = bsum + 128;                   // 128
    int*   wrange  = boff + 128;                   // NWE+1 (pad +8)
    int*   src_d   = wrange + NWE + 8;             // NE
    __half* h16    = (__half*)(src_d + NE);        // NN*64 halfs = 800k floats
    __half* Wt16   = (__half*)((float*)(src_d + NE) + (size_t)NN * 32);  // 3*64*512 halfs

    hipMemsetAsync(d_out, 0, (size_t)NG * NC * sizeof(float), stream);
    hipMemsetAsync(cnt, 0, NN * sizeof(int), stream);

    hist_k<<<(NE + 255) / 256, 256, 0, stream>>>(dst, cnt);
    scan_part_k<<<SCAN_NB, 256, 0, stream>>>(cnt, bsum);
    scan_mid_k<<<1, 128, 0, stream>>>(bsum, boff, dstoff, gids, gcnt);
    scan_final_k<<<SCAN_NB, 256, 0, stream>>>(cnt, boff, dstoff, cur);
    wave_range_k<<<(NWE + 256) / 256, 256, 0, stream>>>(dstoff, wrange);
    scatter_k<<<(NE + 255) / 256, 256, 0, stream>>>(src, dst, cemb, cur, src_d, dnorm_d);
    cast_h16_k<<<(NN * 16 + 255) / 256, 256, 0, stream>>>(feature, h16);
    cast_wt_k<<<(3 * 64 * 512 + 255) / 256, 256, 0, stream>>>(W[0], W[1], W[2], Wt16);

    const float* h_old = feature;
    float* bufs[2] = {bufX, bufY};
    for (int l = 0; l < 3; l++) {
        float* agg = bufs[l & 1];
        edge_E_k<<<NWE / 4, 256, 0, stream>>>(src_d, dstoff, wrange, dnorm_d, h16, E16, sumsN);
        gemm_mfma_k<<<(NN + 15) / 16, 256, 0, stream>>>(E16, Wt16 + (size_t)l * 64 * 512,
                                                        gids, agg, sumsN, sumsqN, XgN);
        if (l < 2) {
            bn_apply_k<<<1024, 256, 0, stream>>>(agg, h_old, sumsN, sumsqN, gam[l], bet[l],
                                                 agg, h16, l > 0, XgN, gcnt, Pold,
                                                 cW1, cb1, cg1, cbt1, cW2, cb2, out);
        } else {
            classifier_only_k<<<1, 256, 0, stream>>>(sumsN, sumsqN, XgN, gcnt, Pold,
                                                     gam[l], bet[l],
                                                     cW1, cb1, cg1, cbt1, cW2, cb2, out);
        }
        h_old = agg;
    }
}

// Round 19
// 406.015 us; speedup vs baseline: 1.0039x; 1.0039x over previous
//
#include <hip/hip_runtime.h>
#include <hip/hip_fp16.h>
#include <math.h>

#define NN 25000
#define NE 400000
#define HD 64
#define EMBD 8
#define NG 16
#define NC 10
#define SCAN_NB 98   // ceil(NN/256)
#define NWE 16384
#define NSL 16       // stat shadow slices (atomic-contention sharding)
#define STATS_F (NSL * 64 + NSL * 64 + NSL * 1024)   // sumsN + sumsqN + XgN

typedef _Float16 f16x8 __attribute__((ext_vector_type(8)));
typedef float f32x4 __attribute__((ext_vector_type(4)));

// ---------------------------------------------------------------------------
// Sort phase: dst-CSR (edge structure is layer-invariant).
// ---------------------------------------------------------------------------
__global__ __launch_bounds__(256) void hist_k(const int* __restrict__ dst, int* cnt) {
    int e = blockIdx.x * 256 + threadIdx.x;
    if (e < NE) atomicAdd(&cnt[dst[e]], 1);
}

__global__ __launch_bounds__(256) void scan_part_k(const int* __restrict__ cnt, int* bsum) {
    __shared__ int sh[256];
    int tx = threadIdx.x;
    int i = blockIdx.x * 256 + tx;
    sh[tx] = (i < NN) ? cnt[i] : 0;
    __syncthreads();
    for (int off = 128; off > 0; off >>= 1) {
        if (tx < off) sh[tx] += sh[tx + off];
        __syncthreads();
    }
    if (tx == 0) bsum[blockIdx.x] = sh[0];
}

// scan of block sums + gcnt[g] via binary search on sorted gids (no atomics:
// sorted ids caused 175us same-bin atomic serialization in R8).
__global__ __launch_bounds__(128) void scan_mid_k(const int* __restrict__ bsum,
        int* boff, int* dstoff, const int* __restrict__ gids, int* gcnt) {
    __shared__ int sh[128];
    int tx = threadIdx.x;
    int v = (tx < SCAN_NB) ? bsum[tx] : 0;
    sh[tx] = v;
    __syncthreads();
    for (int off = 1; off < 128; off <<= 1) {
        int t = (tx >= off) ? sh[tx - off] : 0;
        __syncthreads();
        sh[tx] += t;
        __syncthreads();
    }
    if (tx < SCAN_NB) boff[tx] = sh[tx] - v;
    if (tx == 0) dstoff[NN] = NE;
    if (tx < NG) {
        int lo = 0, hi = NN;
        while (lo < hi) { int m = (lo + hi) >> 1; if (gids[m] < tx) lo = m + 1; else hi = m; }
        int a = lo;
        lo = 0; hi = NN;
        while (lo < hi) { int m = (lo + hi) >> 1; if (gids[m] < tx + 1) lo = m + 1; else hi = m; }
        gcnt[tx] = lo - a;
    }
}

__global__ __launch_bounds__(256) void scan_final_k(const int* __restrict__ cnt,
        const int* __restrict__ boff, int* dstoff, int* cur) {
    __shared__ int sh[256];
    int tx = threadIdx.x;
    int i = blockIdx.x * 256 + tx;
    int v = (i < NN) ? cnt[i] : 0;
    sh[tx] = v;
    __syncthreads();
    for (int off = 1; off < 256; off <<= 1) {
        int t = (tx >= off) ? sh[tx - off] : 0;
        __syncthreads();
        sh[tx] += t;
        __syncthreads();
    }
    int excl = boff[blockIdx.x] + sh[tx] - v;
    if (i < NN) { dstoff[i] = excl; cur[i] = excl; }
}

// ---------------------------------------------------------------------------
// prep_k: everything that depends only on scan_final, fused into one launch:
//   gid < NE      : scatter src to dst-sorted slot + dnorm computation
//   gid < NN*16   : fp16 shadow of layer-0 features
//   gid <= NWE    : per-wave node ranges (binary search, once)
//   gid < 3*64*512: Wt fp16 cast+permute (q' = j*8+i channel-major)
// ---------------------------------------------------------------------------
__global__ __launch_bounds__(256) void prep_k(const int* __restrict__ src,
        const int* __restrict__ dst, const float* __restrict__ c,
        int* cur, const int* __restrict__ dstoff,
        int* __restrict__ src_d, float* __restrict__ dnorm_d,
        const float* __restrict__ feature, __half* __restrict__ h16,
        const float* __restrict__ W0, const float* __restrict__ W1,
        const float* __restrict__ W2, __half* __restrict__ Wt,
        int* __restrict__ wrange) {
    int gid = blockIdx.x * 256 + threadIdx.x;

    if (gid < NE) {
        int s = src[gid], t = dst[gid];
        int pd = atomicAdd(&cur[t], 1);
        src_d[pd] = s;
        float4 sa = *(const float4*)(c + (size_t)s * 8);
        float4 sb = *(const float4*)(c + (size_t)s * 8 + 4);
        float4 na = *(const float4*)(c + (size_t)t * 8);
        float4 nb = *(const float4*)(c + (size_t)t * 8 + 4);
        float d0 = sa.x - na.x, d1 = sa.y - na.y, d2 = sa.z - na.z, d3 = sa.w - na.w;
        float d4 = sb.x - nb.x, d5 = sb.y - nb.y, d6 = sb.z - nb.z, d7 = sb.w - nb.w;
        float nn2 = d0*d0 + d1*d1 + d2*d2 + d3*d3 + d4*d4 + d5*d5 + d6*d6 + d7*d7;
        float inv = 1.f / fmaxf(sqrtf(nn2), 1e-12f);
        *(float4*)(dnorm_d + (size_t)pd * 8)     = make_float4(d0*inv, d1*inv, d2*inv, d3*inv);
        *(float4*)(dnorm_d + (size_t)pd * 8 + 4) = make_float4(d4*inv, d5*inv, d6*inv, d7*inv);
    }
    if (gid < NN * 16) {
        float4 v = *(const float4*)(feature + (size_t)gid * 4);
        __half2 lo = __floats2half2_rn(v.x, v.y);
        __half2 hi = __floats2half2_rn(v.z, v.w);
        *(__half2*)(h16 + (size_t)gid * 4)     = lo;
        *(__half2*)(h16 + (size_t)gid * 4 + 2) = hi;
    }
    if (gid <= NWE) {
        if (gid == NWE) {
            wrange[gid] = NN;
        } else {
            long long t0 = (long long)gid * NE / NWE;
            int lo = 0, hi = NN;
            while (lo < hi) { int m = (lo + hi) >> 1; if (dstoff[m] < t0) lo = m + 1; else hi = m; }
            wrange[gid] = lo;
        }
    }
    if (gid < 3 * 64 * 512) {
        int l = gid >> 15;
        int rem = gid & 32767;
        int k = rem >> 9;
        int qp = rem & 511;
        int ii = qp & 7;
        int jj = qp >> 3;
        const float* W = (l == 0) ? W0 : ((l == 1) ? W1 : W2);
        Wt[gid] = __float2half_rn(W[(size_t)(ii * 64 + jj) * 64 + k]);
    }
}

// ---------------------------------------------------------------------------
// K1: E16[t, q'=j*8+i] = sum_{e->t} dnorm[e,i] * h[src_e, j]
// All control/index/dnorm data is WAVE-UNIFORM -> plain loads let the
// compiler scalarize to s_load on the SMEM pipe (own lgkmcnt counter);
// the vector pipe issues only the one true per-lane op: the h16 gather.
// ---------------------------------------------------------------------------
__global__ __launch_bounds__(256) void edge_E_k(const int* __restrict__ src_d,
        const int* __restrict__ dstoff, const int* __restrict__ wrange,
        const float* __restrict__ dnorm_d,
        const __half* __restrict__ h16, __half* __restrict__ E16,
        float* __restrict__ stats_zero) {
    // zero the sharded stats block cooperatively
    int zstride = gridDim.x * 256;
    for (int t = blockIdx.x * 256 + threadIdx.x; t < STATS_F; t += zstride)
        stats_zero[t] = 0.f;
    int gid  = blockIdx.x * 256 + threadIdx.x;
    int w    = gid >> 6;
    int lane = threadIdx.x & 63;
    int nlo = wrange[w];
    int nhi = wrange[w + 1];

    for (int n = nlo; n < nhi; n++) {
        float e0=0,e1=0,e2=0,e3=0,e4=0,e5=0,e6=0,e7=0;
        int p0 = dstoff[n], p1 = dstoff[n + 1];
        for (int p = p0; p < p1; p += 8) {
            int m = p1 - p;             // wave-uniform
            int pj[8]; int sj[8]; __half hj[8];
#pragma unroll
            for (int j = 0; j < 8; j++) {
                int q = p + j; if (q > p1 - 1) q = p1 - 1;   // clamp (dup ok)
                pj[j] = q;
                sj[j] = src_d[q];       // uniform -> s_load
            }
#pragma unroll
            for (int j = 0; j < 8; j++)
                hj[j] = h16[(size_t)sj[j] * 64 + lane];      // 8 gathers in flight
#pragma unroll
            for (int j = 0; j < 8; j++)
                if (j < m) {
                    float4 dA = *(const float4*)(dnorm_d + (size_t)pj[j] * 8);
                    float4 dB = *(const float4*)(dnorm_d + (size_t)pj[j] * 8 + 4);
                    float hv = __half2float(hj[j]);
                    e0 = fmaf(dA.x, hv, e0); e1 = fmaf(dA.y, hv, e1);
                    e2 = fmaf(dA.z, hv, e2); e3 = fmaf(dA.w, hv, e3);
                    e4 = fmaf(dB.x, hv, e4); e5 = fmaf(dB.y, hv, e5);
                    e6 = fmaf(dB.z, hv, e6); e7 = fmaf(dB.w, hv, e7);
                }
        }
        float4 pack;
        ((__half2*)&pack)[0] = __floats2half2_rn(e0, e1);
        ((__half2*)&pack)[1] = __floats2half2_rn(e2, e3);
        ((__half2*)&pack)[2] = __floats2half2_rn(e4, e5);
        ((__half2*)&pack)[3] = __floats2half2_rn(e6, e7);
        *(float4*)(E16 + (size_t)n * 512 + lane * 8) = pack;
    }
}

// ---------------------------------------------------------------------------
// K2 (MFMA): agg[n,k] = sum_q' E16[n,q'] * Wt16[k,q'], fp32 accumulate.
// Stats go to shadow slice (blockIdx & 15).
// ---------------------------------------------------------------------------
__global__ __launch_bounds__(256) void gemm_mfma_k(const __half* __restrict__ E16,
        const __half* __restrict__ Wt16, const int* __restrict__ gids,
        float* __restrict__ agg, float* __restrict__ sumsN,
        float* __restrict__ sumsqN, float* __restrict__ XgN) {
    __shared__ float pl[NG * 64];
    __shared__ float s1[64], s2[64];
    __shared__ int gsh[16];
    int tx = threadIdx.x;
    int wave = tx >> 6, lane = tx & 63;
    int n0 = blockIdx.x * 16;
    int c0 = wave * 16;
    int slice = blockIdx.x & (NSL - 1);
    for (int t = tx; t < NG * 64; t += 256) pl[t] = 0.f;
    if (tx < 64) { s1[tx] = 0.f; s2[tx] = 0.f; }
    if (tx < 16) gsh[tx] = gids[min(n0 + tx, NN - 1)];
    __syncthreads();

    int quad = lane >> 4;
    int lcol = lane & 15;
    int ar = n0 + lcol; if (ar > NN - 1) ar = NN - 1;
    const f16x8* pa = (const f16x8*)(E16 + (size_t)ar * 512 + quad * 8);
    const f16x8* pb = (const f16x8*)(Wt16 + (size_t)(c0 + lcol) * 512 + quad * 8);
    f32x4 acc = {0.f, 0.f, 0.f, 0.f};
#pragma unroll
    for (int kc = 0; kc < 16; kc++) {
        f16x8 a = pa[kc * 4];
        f16x8 b = pb[kc * 4];
        acc = __builtin_amdgcn_mfma_f32_16x16x32_f16(a, b, acc, 0, 0, 0);
    }

    int colg = c0 + lcol;
    float s1l = 0.f, s2l = 0.f;
#pragma unroll
    for (int r = 0; r < 4; r++) {
        int nrow = quad * 4 + r;
        int n = n0 + nrow;
        if (n < NN) {
            float v = acc[r];
            agg[(size_t)n * 64 + colg] = v;
            float x = fmaxf(v, 0.f);
            s1l += x; s2l += x * x;
            atomicAdd(&pl[gsh[nrow] * 64 + colg], x);
        }
    }
    atomicAdd(&s1[colg], s1l);
    atomicAdd(&s2[colg], s2l);
    __syncthreads();
    if (tx < 64) {
        atomicAdd(&sumsN[slice * 64 + tx], s1[tx]);
        atomicAdd(&sumsqN[slice * 64 + tx], s2[tx]);
    }
    for (int t = tx; t < NG * 64; t += 256) {
        float v = pl[t];
        if (v != 0.f) atomicAdd(&XgN[slice * 1024 + t], v);
    }
}

// ---------------------------------------------------------------------------
// Classifier via pooled-BN identity; stats summed over NSL shadow slices.
// ---------------------------------------------------------------------------
__device__ __forceinline__ void classifier_body(int tx,
        const float* __restrict__ sumsN, const float* __restrict__ sumsqN,
        const float* __restrict__ XgN, const int* __restrict__ gcnt,
        float* __restrict__ Pold,
        const float* __restrict__ gamma, const float* __restrict__ beta,
        const float* __restrict__ cW1, const float* __restrict__ cb1,
        const float* __restrict__ cg1, const float* __restrict__ cbt1,
        const float* __restrict__ cW2, const float* __restrict__ cb2,
        float* __restrict__ logits, int sc) {
    __shared__ float Pn[NG * 64];
    __shared__ float H1s[NG * 32];
    __shared__ float cmu[32], crs[32];
    for (int t = tx; t < NG * 64; t += 256) {
        int g = t >> 6, k = t & 63;
        float sk = 0.f, sq = 0.f, xg = 0.f;
#pragma unroll
        for (int s = 0; s < NSL; s++) {
            sk += sumsN[s * 64 + k];
            sq += sumsqN[s * 64 + k];
            xg += XgN[s * 1024 + t];
        }
        float mean = sk * (1.f / NN);
        float var  = sq * (1.f / NN) - mean * mean;
        float r = rsqrtf(var + 1e-5f);
        float cg = (float)gcnt[g];
        float v = gamma[k] * r * (xg - cg * mean) + cg * beta[k];
        if (sc) v += Pold[t];
        Pn[t] = v;
        Pold[t] = v;
    }
    __syncthreads();
    for (int t = tx; t < NG * 32; t += 256) {
        int g = t >> 5, c = t & 31;
        float acc = cb1[c];
#pragma unroll 16
        for (int j = 0; j < 64; j++) acc = fmaf(Pn[g * 64 + j], cW1[j * 32 + c], acc);
        H1s[t] = acc;
    }
    __syncthreads();
    if (tx < 32) {
        float mu = 0.f;
#pragma unroll
        for (int g2 = 0; g2 < NG; g2++) mu += H1s[g2 * 32 + tx];
        mu *= (1.f / NG);
        float v = 0.f;
#pragma unroll
        for (int g2 = 0; g2 < NG; g2++) {
            float d = H1s[g2 * 32 + tx] - mu;
            v += d * d;
        }
        v *= (1.f / NG);
        cmu[tx] = mu;
        crs[tx] = rsqrtf(v + 1e-5f);
    }
    __syncthreads();
    for (int t = tx; t < NG * 32; t += 256) {
        int c = t & 31;
        H1s[t] = fmaxf(cg1[c] * (H1s[t] - cmu[c]) * crs[c] + cbt1[c], 0.f);
    }
    __syncthreads();
    if (tx < NG * NC) {
        int g = tx / NC, cls = tx % NC;
        float a2 = cb2[cls];
#pragma unroll
        for (int j = 0; j < 32; j++) a2 = fmaf(H1s[g * 32 + j], cW2[j * NC + cls], a2);
        logits[tx] += a2;
    }
}

// ---------------------------------------------------------------------------
// K4: BN apply + shortcut -> h_new (fp32) + fp16 shadow; float4 I/O;
// block 0 also runs the classifier.
// ---------------------------------------------------------------------------
__global__ __launch_bounds__(256) void bn_apply_k(const float* __restrict__ agg,
        const float* __restrict__ h_old, const float* __restrict__ sumsN,
        const float* __restrict__ sumsqN, const float* __restrict__ gamma,
        const float* __restrict__ beta, float* __restrict__ h_new,
        __half* __restrict__ h16_out, int shortcut,
        const float* __restrict__ XgN, const int* __restrict__ gcnt,
        float* __restrict__ Pold,
        const float* __restrict__ cW1, const float* __restrict__ cb1,
        const float* __restrict__ cg1, const float* __restrict__ cbt1,
        const float* __restrict__ cW2, const float* __restrict__ cb2,
        float* __restrict__ logits) {
    int tx = threadIdx.x;
    int col0 = (tx & 15) * 4;
    float mean[4], rstd[4], gv[4], bv[4];
#pragma unroll
    for (int cc = 0; cc < 4; cc++) {
        int k = col0 + cc;
        float sk = 0.f, sq = 0.f;
#pragma unroll
        for (int s = 0; s < NSL; s++) {
            sk += sumsN[s * 64 + k];
            sq += sumsqN[s * 64 + k];
        }
        float mu = sk * (1.f / NN);
        float var = sq * (1.f / NN) - mu * mu;
        mean[cc] = mu;
        rstd[cc] = rsqrtf(var + 1e-5f);
        gv[cc] = gamma[k];
        bv[cc] = beta[k];
    }
    int row = blockIdx.x * 16 + (tx >> 4);
    int rstride = gridDim.x * 16;
    for (int n = row; n < NN; n += rstride) {
        float4 x4 = *(const float4*)(agg + (size_t)n * 64 + col0);
        float y[4] = {x4.x, x4.y, x4.z, x4.w};
#pragma unroll
        for (int cc = 0; cc < 4; cc++) {
            float x = fmaxf(y[cc], 0.f);
            y[cc] = gv[cc] * (x - mean[cc]) * rstd[cc] + bv[cc];
        }
        if (shortcut) {
            float4 h4 = *(const float4*)(h_old + (size_t)n * 64 + col0);
            y[0] += h4.x; y[1] += h4.y; y[2] += h4.z; y[3] += h4.w;
        }
        *(float4*)(h_new + (size_t)n * 64 + col0) = make_float4(y[0], y[1], y[2], y[3]);
        float2 pk;
        ((__half2*)&pk)[0] = __floats2half2_rn(y[0], y[1]);
        ((__half2*)&pk)[1] = __floats2half2_rn(y[2], y[3]);
        *(float2*)(h16_out + (size_t)n * 64 + col0) = pk;
    }
    if (blockIdx.x == 0)
        classifier_body(tx, sumsN, sumsqN, XgN, gcnt, Pold, gamma, beta,
                        cW1, cb1, cg1, cbt1, cW2, cb2, logits, shortcut);
}

// Layer 2: h_new never consumed -> classifier only (1 block).
__global__ __launch_bounds__(256) void classifier_only_k(
        const float* __restrict__ sumsN, const float* __restrict__ sumsqN,
        const float* __restrict__ XgN, const int* __restrict__ gcnt,
        float* __restrict__ Pold,
        const float* __restrict__ gamma, const float* __restrict__ beta,
        const float* __restrict__ cW1, const float* __restrict__ cb1,
        const float* __restrict__ cg1, const float* __restrict__ cbt1,
        const float* __restrict__ cW2, const float* __restrict__ cb2,
        float* __restrict__ logits) {
    classifier_body(threadIdx.x, sumsN, sumsqN, XgN, gcnt, Pold, gamma, beta,
                    cW1, cb1, cg1, cbt1, cW2, cb2, logits, 1);
}

// ---------------------------------------------------------------------------
extern "C" void kernel_launch(void* const* d_in, const int* in_sizes, int n_in,
                              void* d_out, int out_size, void* d_ws, size_t ws_size,
                              hipStream_t stream) {
    const float* feature = (const float*)d_in[0];
    const float* cemb    = (const float*)d_in[1];
    const int*   src     = (const int*)d_in[2];
    const int*   dst     = (const int*)d_in[3];
    const int*   gids    = (const int*)d_in[4];
    const float* W[3]    = {(const float*)d_in[5], (const float*)d_in[6], (const float*)d_in[7]};
    const float* gam[3]  = {(const float*)d_in[8], (const float*)d_in[10], (const float*)d_in[12]};
    const float* bet[3]  = {(const float*)d_in[9], (const float*)d_in[11], (const float*)d_in[13]};
    const float* cW1  = (const float*)d_in[14];
    const float* cb1  = (const float*)d_in[15];
    const float* cg1  = (const float*)d_in[16];
    const float* cbt1 = (const float*)d_in[17];
    const float* cW2  = (const float*)d_in[18];
    const float* cb2  = (const float*)d_in[19];
    float* out = (float*)d_out;

    // workspace layout (4-byte units)
    float* ws      = (float*)d_ws;
    __half* E16    = (__half*)ws;                  // NN*512 halfs = 6.4M floats
    float* dnorm_d = ws + (size_t)NN * 256;        // NE*8 = 3.2M
    float* bufX    = dnorm_d + (size_t)NE * 8;     // NN*64
    float* bufY    = bufX + (size_t)NN * 64;       // NN*64
    float* sumsN   = bufY + (size_t)NN * 64;       // NSL*64   } contiguous,
    float* sumsqN  = sumsN + NSL * 64;             // NSL*64   } zeroed by edge_E
    float* XgN     = sumsqN + NSL * 64;            // NSL*1024 }
    float* Pold    = sumsN + STATS_F;              // 1024 (persists across layers)
    int*   cnt     = (int*)(Pold + 1024);          // NN
    int*   gcnt    = cnt + NN;                     // 16
    int*   cur     = gcnt + 16;                    // NN
    int*   dstoff  = cur + NN;                     // NN+1 (pad +8)
    int*   bsum    = dstoff + NN + 8;              // 128
    int*   boff    = bsum + 128;                   // 128
    int*   wrange  = boff + 128;                   // NWE+1 (pad +8)
    int*   src_d   = wrange + NWE + 8;             // NE
    __half* h16    = (__half*)(src_d + NE);        // NN*64 halfs = 800k floats
    __half* Wt16   = (__half*)((float*)(src_d + NE) + (size_t)NN * 32);  // 3*64*512 halfs

    hipMemsetAsync(d_out, 0, (size_t)NG * NC * sizeof(float), stream);
    hipMemsetAsync(cnt, 0, NN * sizeof(int), stream);

    hist_k<<<(NE + 255) / 256, 256, 0, stream>>>(dst, cnt);
    scan_part_k<<<SCAN_NB, 256, 0, stream>>>(cnt, bsum);
    scan_mid_k<<<1, 128, 0, stream>>>(bsum, boff, dstoff, gids, gcnt);
    scan_final_k<<<SCAN_NB, 256, 0, stream>>>(cnt, boff, dstoff, cur);
    prep_k<<<(NE + 255) / 256, 256, 0, stream>>>(src, dst, cemb, cur, dstoff,
                                                 src_d, dnorm_d, feature, h16,
                                                 W[0], W[1], W[2], Wt16, wrange);

    const float* h_old = feature;
    float* bufs[2] = {bufX, bufY};
    for (int l = 0; l < 3; l++) {
        float* agg = bufs[l & 1];
        edge_E_k<<<NWE / 4, 256, 0, stream>>>(src_d, dstoff, wrange, dnorm_d, h16, E16, sumsN);
        gemm_mfma_k<<<(NN + 15) / 16, 256, 0, stream>>>(E16, Wt16 + (size_t)l * 64 * 512,
                                                        gids, agg, sumsN, sumsqN, XgN);
        if (l < 2) {
            bn_apply_k<<<1024, 256, 0, stream>>>(agg, h_old, sumsN, sumsqN, gam[l], bet[l],
                                                 agg, h16, l > 0, XgN, gcnt, Pold,
                                                 cW1, cb1, cg1, cbt1, cW2, cb2, out);
        } else {
            classifier_only_k<<<1, 256, 0, stream>>>(sumsN, sumsqN, XgN, gcnt, Pold,
                                                     gam[l], bet[l],
                                                     cW1, cb1, cg1, cbt1, cW2, cb2, out);
        }
        h_old = agg;
    }
}

// Round 20
// 362.144 us; speedup vs baseline: 1.1255x; 1.1211x over previous
//
#include <hip/hip_runtime.h>
#include <hip/hip_fp16.h>
#include <math.h>

#define NN 25000
#define NE 400000
#define HD 64
#define EMBD 8
#define NG 16
#define NC 10
#define SCAN_NB 98   // ceil(NN/256)
#define NSL 16       // stat shadow slices (atomic-contention sharding)
#define STATS_F (NSL * 64 + NSL * 64 + NSL * 1024)   // sumsN + sumsqN + XgN

typedef _Float16 f16x8 __attribute__((ext_vector_type(8)));
typedef float f32x4 __attribute__((ext_vector_type(4)));

// ---------------------------------------------------------------------------
// Sort phase: dst-CSR (edge structure is layer-invariant).
// ---------------------------------------------------------------------------
__global__ __launch_bounds__(256) void hist_k(const int* __restrict__ dst, int* cnt) {
    int e = blockIdx.x * 256 + threadIdx.x;
    if (e < NE) atomicAdd(&cnt[dst[e]], 1);
}

__global__ __launch_bounds__(256) void scan_part_k(const int* __restrict__ cnt, int* bsum) {
    __shared__ int sh[256];
    int tx = threadIdx.x;
    int i = blockIdx.x * 256 + tx;
    sh[tx] = (i < NN) ? cnt[i] : 0;
    __syncthreads();
    for (int off = 128; off > 0; off >>= 1) {
        if (tx < off) sh[tx] += sh[tx + off];
        __syncthreads();
    }
    if (tx == 0) bsum[blockIdx.x] = sh[0];
}

// scan of block sums + gcnt[g] via binary search on sorted gids (no atomics:
// sorted ids caused 175us same-bin atomic serialization in R8).
__global__ __launch_bounds__(128) void scan_mid_k(const int* __restrict__ bsum,
        int* boff, int* dstoff, const int* __restrict__ gids, int* gcnt) {
    __shared__ int sh[128];
    int tx = threadIdx.x;
    int v = (tx < SCAN_NB) ? bsum[tx] : 0;
    sh[tx] = v;
    __syncthreads();
    for (int off = 1; off < 128; off <<= 1) {
        int t = (tx >= off) ? sh[tx - off] : 0;
        __syncthreads();
        sh[tx] += t;
        __syncthreads();
    }
    if (tx < SCAN_NB) boff[tx] = sh[tx] - v;
    if (tx == 0) dstoff[NN] = NE;
    if (tx < NG) {
        int lo = 0, hi = NN;
        while (lo < hi) { int m = (lo + hi) >> 1; if (gids[m] < tx) lo = m + 1; else hi = m; }
        int a = lo;
        lo = 0; hi = NN;
        while (lo < hi) { int m = (lo + hi) >> 1; if (gids[m] < tx + 1) lo = m + 1; else hi = m; }
        gcnt[tx] = lo - a;
    }
}

__global__ __launch_bounds__(256) void scan_final_k(const int* __restrict__ cnt,
        const int* __restrict__ boff, int* dstoff, int* cur) {
    __shared__ int sh[256];
    int tx = threadIdx.x;
    int i = blockIdx.x * 256 + tx;
    int v = (i < NN) ? cnt[i] : 0;
    sh[tx] = v;
    __syncthreads();
    for (int off = 1; off < 256; off <<= 1) {
        int t = (tx >= off) ? sh[tx - off] : 0;
        __syncthreads();
        sh[tx] += t;
        __syncthreads();
    }
    int excl = boff[blockIdx.x] + sh[tx] - v;
    if (i < NN) { dstoff[i] = excl; cur[i] = excl; }
}

// ---------------------------------------------------------------------------
// prep_k: everything that depends only on scan_final, fused:
//   gid < NE        : scatter src to dst-sorted slot + dnorm computation
//   gid < NN*16     : fp16 shadow of layer-0 features
//   gid < 3*STATS_F : zero the 3 per-layer stats buffers (separate buffers
//                     per layer because zeroing now can't overlap the fused
//                     edge+gemm kernel's accumulation)
//   gid < 3*64*512  : Wt fp16 cast+permute (q' = j*8+i channel-major)
// ---------------------------------------------------------------------------
__global__ __launch_bounds__(256) void prep_k(const int* __restrict__ src,
        const int* __restrict__ dst, const float* __restrict__ c,
        int* cur, int* __restrict__ src_d, float* __restrict__ dnorm_d,
        const float* __restrict__ feature, __half* __restrict__ h16,
        const float* __restrict__ W0, const float* __restrict__ W1,
        const float* __restrict__ W2, __half* __restrict__ Wt,
        float* __restrict__ statsAll) {
    int gid = blockIdx.x * 256 + threadIdx.x;

    if (gid < NE) {
        int s = src[gid], t = dst[gid];
        int pd = atomicAdd(&cur[t], 1);
        src_d[pd] = s;
        float4 sa = *(const float4*)(c + (size_t)s * 8);
        float4 sb = *(const float4*)(c + (size_t)s * 8 + 4);
        float4 na = *(const float4*)(c + (size_t)t * 8);
        float4 nb = *(const float4*)(c + (size_t)t * 8 + 4);
        float d0 = sa.x - na.x, d1 = sa.y - na.y, d2 = sa.z - na.z, d3 = sa.w - na.w;
        float d4 = sb.x - nb.x, d5 = sb.y - nb.y, d6 = sb.z - nb.z, d7 = sb.w - nb.w;
        float nn2 = d0*d0 + d1*d1 + d2*d2 + d3*d3 + d4*d4 + d5*d5 + d6*d6 + d7*d7;
        float inv = 1.f / fmaxf(sqrtf(nn2), 1e-12f);
        *(float4*)(dnorm_d + (size_t)pd * 8)     = make_float4(d0*inv, d1*inv, d2*inv, d3*inv);
        *(float4*)(dnorm_d + (size_t)pd * 8 + 4) = make_float4(d4*inv, d5*inv, d6*inv, d7*inv);
    }
    if (gid < NN * 16) {
        float4 v = *(const float4*)(feature + (size_t)gid * 4);
        __half2 lo = __floats2half2_rn(v.x, v.y);
        __half2 hi = __floats2half2_rn(v.z, v.w);
        *(__half2*)(h16 + (size_t)gid * 4)     = lo;
        *(__half2*)(h16 + (size_t)gid * 4 + 2) = hi;
    }
    if (gid < 3 * STATS_F) statsAll[gid] = 0.f;
    if (gid < 3 * 64 * 512) {
        int l = gid >> 15;
        int rem = gid & 32767;
        int k = rem >> 9;
        int qp = rem & 511;
        int ii = qp & 7;
        int jj = qp >> 3;
        const float* W = (l == 0) ? W0 : ((l == 1) ? W1 : W2);
        Wt[gid] = __float2half_rn(W[(size_t)(ii * 64 + jj) * 64 + k]);
    }
}

// ---------------------------------------------------------------------------
// FUSED edge gather + MFMA GEMM (replaces edge_E_k + gemm_mfma_k).
// Block = 16 nodes. Phase 1: wave w gathers edges for nodes n0+4w..+3
// (uniform s_load indices, 8 gathers in flight), accumulates E rows in
// registers, writes the 16x512 fp16 tile to LDS (row pad 520 halfs:
// b128 reads land 2-way, free per m136). Phase 2: wave w computes cols
// 16w..16w+15 via 16x mfma_f32_16x16x32_f16, A from LDS, B from L2-resident
// Wt16. Kills the E global round-trip (50 MB/layer) and one dispatch/layer.
// Epilogue: relu BN-stats + per-graph Xg into per-layer sharded buffers.
// ---------------------------------------------------------------------------
__global__ __launch_bounds__(256) void edge_gemm_k(const int* __restrict__ src_d,
        const int* __restrict__ dstoff, const float* __restrict__ dnorm_d,
        const __half* __restrict__ h16, const __half* __restrict__ Wt16,
        const int* __restrict__ gids, float* __restrict__ agg,
        float* __restrict__ sumsN, float* __restrict__ sumsqN,
        float* __restrict__ XgN) {
    __shared__ __half Esh[16][520];   // padded: 1040B row
    __shared__ float pl[NG * 64];
    __shared__ float s1[64], s2[64];
    __shared__ int gsh[16];
    int tx = threadIdx.x;
    int wave = tx >> 6, lane = tx & 63;
    int n0 = blockIdx.x * 16;
    int slice = blockIdx.x & (NSL - 1);
    for (int t = tx; t < NG * 64; t += 256) pl[t] = 0.f;
    if (tx < 64) { s1[tx] = 0.f; s2[tx] = 0.f; }
    if (tx < 16) gsh[tx] = gids[min(n0 + tx, NN - 1)];

    // ---- phase 1: gather 4 nodes per wave ----
#pragma unroll
    for (int i = 0; i < 4; i++) {
        int nloc = wave * 4 + i;
        int n = n0 + nloc;
        float e0=0,e1=0,e2=0,e3=0,e4=0,e5=0,e6=0,e7=0;
        if (n < NN) {
            int p0 = dstoff[n], p1 = dstoff[n + 1];
            for (int p = p0; p < p1; p += 8) {
                int m = p1 - p;             // wave-uniform
                int pj[8]; int sj[8]; __half hj[8];
#pragma unroll
                for (int j = 0; j < 8; j++) {
                    int q = p + j; if (q > p1 - 1) q = p1 - 1;
                    pj[j] = q;
                    sj[j] = src_d[q];       // uniform -> s_load
                }
#pragma unroll
                for (int j = 0; j < 8; j++)
                    hj[j] = h16[(size_t)sj[j] * 64 + lane];
#pragma unroll
                for (int j = 0; j < 8; j++)
                    if (j < m) {
                        float4 dA = *(const float4*)(dnorm_d + (size_t)pj[j] * 8);
                        float4 dB = *(const float4*)(dnorm_d + (size_t)pj[j] * 8 + 4);
                        float hv = __half2float(hj[j]);
                        e0 = fmaf(dA.x, hv, e0); e1 = fmaf(dA.y, hv, e1);
                        e2 = fmaf(dA.z, hv, e2); e3 = fmaf(dA.w, hv, e3);
                        e4 = fmaf(dB.x, hv, e4); e5 = fmaf(dB.y, hv, e5);
                        e6 = fmaf(dB.z, hv, e6); e7 = fmaf(dB.w, hv, e7);
                    }
            }
        }
        float4 pack;
        ((__half2*)&pack)[0] = __floats2half2_rn(e0, e1);
        ((__half2*)&pack)[1] = __floats2half2_rn(e2, e3);
        ((__half2*)&pack)[2] = __floats2half2_rn(e4, e5);
        ((__half2*)&pack)[3] = __floats2half2_rn(e6, e7);
        *(float4*)&Esh[nloc][lane * 8] = pack;
    }
    __syncthreads();

    // ---- phase 2: MFMA, A from LDS, B from global ----
    int quad = lane >> 4;
    int lcol = lane & 15;
    int c0 = wave * 16;
    const f16x8* pb = (const f16x8*)(Wt16 + (size_t)(c0 + lcol) * 512 + quad * 8);
    f32x4 acc = {0.f, 0.f, 0.f, 0.f};
#pragma unroll
    for (int kc = 0; kc < 16; kc++) {
        f16x8 a = *(const f16x8*)&Esh[lcol][kc * 32 + quad * 8];
        f16x8 b = pb[kc * 4];
        acc = __builtin_amdgcn_mfma_f32_16x16x32_f16(a, b, acc, 0, 0, 0);
    }

    int colg = c0 + lcol;
    float s1l = 0.f, s2l = 0.f;
#pragma unroll
    for (int r = 0; r < 4; r++) {
        int nrow = quad * 4 + r;
        int n = n0 + nrow;
        if (n < NN) {
            float v = acc[r];
            agg[(size_t)n * 64 + colg] = v;
            float x = fmaxf(v, 0.f);
            s1l += x; s2l += x * x;
            atomicAdd(&pl[gsh[nrow] * 64 + colg], x);
        }
    }
    atomicAdd(&s1[colg], s1l);
    atomicAdd(&s2[colg], s2l);
    __syncthreads();
    if (tx < 64) {
        atomicAdd(&sumsN[slice * 64 + tx], s1[tx]);
        atomicAdd(&sumsqN[slice * 64 + tx], s2[tx]);
    }
    for (int t = tx; t < NG * 64; t += 256) {
        float v = pl[t];
        if (v != 0.f) atomicAdd(&XgN[slice * 1024 + t], v);
    }
}

// ---------------------------------------------------------------------------
// Classifier via pooled-BN identity; stats summed over NSL shadow slices.
// ---------------------------------------------------------------------------
__device__ __forceinline__ void classifier_body(int tx,
        const float* __restrict__ sumsN, const float* __restrict__ sumsqN,
        const float* __restrict__ XgN, const int* __restrict__ gcnt,
        float* __restrict__ Pold,
        const float* __restrict__ gamma, const float* __restrict__ beta,
        const float* __restrict__ cW1, const float* __restrict__ cb1,
        const float* __restrict__ cg1, const float* __restrict__ cbt1,
        const float* __restrict__ cW2, const float* __restrict__ cb2,
        float* __restrict__ logits, int sc) {
    __shared__ float Pn[NG * 64];
    __shared__ float H1s[NG * 32];
    __shared__ float cmu[32], crs[32];
    for (int t = tx; t < NG * 64; t += 256) {
        int g = t >> 6, k = t & 63;
        float sk = 0.f, sq = 0.f, xg = 0.f;
#pragma unroll
        for (int s = 0; s < NSL; s++) {
            sk += sumsN[s * 64 + k];
            sq += sumsqN[s * 64 + k];
            xg += XgN[s * 1024 + t];
        }
        float mean = sk * (1.f / NN);
        float var  = sq * (1.f / NN) - mean * mean;
        float r = rsqrtf(var + 1e-5f);
        float cg = (float)gcnt[g];
        float v = gamma[k] * r * (xg - cg * mean) + cg * beta[k];
        if (sc) v += Pold[t];
        Pn[t] = v;
        Pold[t] = v;
    }
    __syncthreads();
    for (int t = tx; t < NG * 32; t += 256) {
        int g = t >> 5, c = t & 31;
        float acc = cb1[c];
#pragma unroll 16
        for (int j = 0; j < 64; j++) acc = fmaf(Pn[g * 64 + j], cW1[j * 32 + c], acc);
        H1s[t] = acc;
    }
    __syncthreads();
    if (tx < 32) {
        float mu = 0.f;
#pragma unroll
        for (int g2 = 0; g2 < NG; g2++) mu += H1s[g2 * 32 + tx];
        mu *= (1.f / NG);
        float v = 0.f;
#pragma unroll
        for (int g2 = 0; g2 < NG; g2++) {
            float d = H1s[g2 * 32 + tx] - mu;
            v += d * d;
        }
        v *= (1.f / NG);
        cmu[tx] = mu;
        crs[tx] = rsqrtf(v + 1e-5f);
    }
    __syncthreads();
    for (int t = tx; t < NG * 32; t += 256) {
        int c = t & 31;
        H1s[t] = fmaxf(cg1[c] * (H1s[t] - cmu[c]) * crs[c] + cbt1[c], 0.f);
    }
    __syncthreads();
    if (tx < NG * NC) {
        int g = tx / NC, cls = tx % NC;
        float a2 = cb2[cls];
#pragma unroll
        for (int j = 0; j < 32; j++) a2 = fmaf(H1s[g * 32 + j], cW2[j * NC + cls], a2);
        logits[tx] += a2;
    }
}

// ---------------------------------------------------------------------------
// K4: BN apply + shortcut -> h_new (fp32) + fp16 shadow; float4 I/O;
// block 0 also runs the classifier.
// ---------------------------------------------------------------------------
__global__ __launch_bounds__(256) void bn_apply_k(const float* __restrict__ agg,
        const float* __restrict__ h_old, const float* __restrict__ sumsN,
        const float* __restrict__ sumsqN, const float* __restrict__ gamma,
        const float* __restrict__ beta, float* __restrict__ h_new,
        __half* __restrict__ h16_out, int shortcut,
        const float* __restrict__ XgN, const int* __restrict__ gcnt,
        float* __restrict__ Pold,
        const float* __restrict__ cW1, const float* __restrict__ cb1,
        const float* __restrict__ cg1, const float* __restrict__ cbt1,
        const float* __restrict__ cW2, const float* __restrict__ cb2,
        float* __restrict__ logits) {
    int tx = threadIdx.x;
    int col0 = (tx & 15) * 4;
    float mean[4], rstd[4], gv[4], bv[4];
#pragma unroll
    for (int cc = 0; cc < 4; cc++) {
        int k = col0 + cc;
        float sk = 0.f, sq = 0.f;
#pragma unroll
        for (int s = 0; s < NSL; s++) {
            sk += sumsN[s * 64 + k];
            sq += sumsqN[s * 64 + k];
        }
        float mu = sk * (1.f / NN);
        float var = sq * (1.f / NN) - mu * mu;
        mean[cc] = mu;
        rstd[cc] = rsqrtf(var + 1e-5f);
        gv[cc] = gamma[k];
        bv[cc] = beta[k];
    }
    int row = blockIdx.x * 16 + (tx >> 4);
    int rstride = gridDim.x * 16;
    for (int n = row; n < NN; n += rstride) {
        float4 x4 = *(const float4*)(agg + (size_t)n * 64 + col0);
        float y[4] = {x4.x, x4.y, x4.z, x4.w};
#pragma unroll
        for (int cc = 0; cc < 4; cc++) {
            float x = fmaxf(y[cc], 0.f);
            y[cc] = gv[cc] * (x - mean[cc]) * rstd[cc] + bv[cc];
        }
        if (shortcut) {
            float4 h4 = *(const float4*)(h_old + (size_t)n * 64 + col0);
            y[0] += h4.x; y[1] += h4.y; y[2] += h4.z; y[3] += h4.w;
        }
        *(float4*)(h_new + (size_t)n * 64 + col0) = make_float4(y[0], y[1], y[2], y[3]);
        float2 pk;
        ((__half2*)&pk)[0] = __floats2half2_rn(y[0], y[1]);
        ((__half2*)&pk)[1] = __floats2half2_rn(y[2], y[3]);
        *(float2*)(h16_out + (size_t)n * 64 + col0) = pk;
    }
    if (blockIdx.x == 0)
        classifier_body(tx, sumsN, sumsqN, XgN, gcnt, Pold, gamma, beta,
                        cW1, cb1, cg1, cbt1, cW2, cb2, logits, shortcut);
}

// Layer 2: h_new never consumed -> classifier only (1 block).
__global__ __launch_bounds__(256) void classifier_only_k(
        const float* __restrict__ sumsN, const float* __restrict__ sumsqN,
        const float* __restrict__ XgN, const int* __restrict__ gcnt,
        float* __restrict__ Pold,
        const float* __restrict__ gamma, const float* __restrict__ beta,
        const float* __restrict__ cW1, const float* __restrict__ cb1,
        const float* __restrict__ cg1, const float* __restrict__ cbt1,
        const float* __restrict__ cW2, const float* __restrict__ cb2,
        float* __restrict__ logits) {
    classifier_body(threadIdx.x, sumsN, sumsqN, XgN, gcnt, Pold, gamma, beta,
                    cW1, cb1, cg1, cbt1, cW2, cb2, logits, 1);
}

// ---------------------------------------------------------------------------
extern "C" void kernel_launch(void* const* d_in, const int* in_sizes, int n_in,
                              void* d_out, int out_size, void* d_ws, size_t ws_size,
                              hipStream_t stream) {
    const float* feature = (const float*)d_in[0];
    const float* cemb    = (const float*)d_in[1];
    const int*   src     = (const int*)d_in[2];
    const int*   dst     = (const int*)d_in[3];
    const int*   gids    = (const int*)d_in[4];
    const float* W[3]    = {(const float*)d_in[5], (const float*)d_in[6], (const float*)d_in[7]};
    const float* gam[3]  = {(const float*)d_in[8], (const float*)d_in[10], (const float*)d_in[12]};
    const float* bet[3]  = {(const float*)d_in[9], (const float*)d_in[11], (const float*)d_in[13]};
    const float* cW1  = (const float*)d_in[14];
    const float* cb1  = (const float*)d_in[15];
    const float* cg1  = (const float*)d_in[16];
    const float* cbt1 = (const float*)d_in[17];
    const float* cW2  = (const float*)d_in[18];
    const float* cb2  = (const float*)d_in[19];
    float* out = (float*)d_out;

    // workspace layout (4-byte units)
    float* ws       = (float*)d_ws;
    float* dnorm_d  = ws;                          // NE*8 = 3.2M
    float* bufX     = dnorm_d + (size_t)NE * 8;    // NN*64
    float* bufY     = bufX + (size_t)NN * 64;      // NN*64
    float* statsAll = bufY + (size_t)NN * 64;      // 3*STATS_F (zeroed in prep)
    float* Pold     = statsAll + 3 * STATS_F;      // 1024 (persists across layers)
    int*   cnt      = (int*)(Pold + 1024);         // NN
    int*   gcnt     = cnt + NN;                    // 16
    int*   cur      = gcnt + 16;                   // NN
    int*   dstoff   = cur + NN;                    // NN+1 (pad +8)
    int*   bsum     = dstoff + NN + 8;             // 128
    int*   boff     = bsum + 128;                  // 128
    int*   src_d    = boff + 128;                  // NE
    __half* h16     = (__half*)(src_d + NE);       // NN*64 halfs
    __half* Wt16    = (__half*)((float*)(src_d + NE) + (size_t)NN * 32);  // 3*64*512 halfs

    hipMemsetAsync(d_out, 0, (size_t)NG * NC * sizeof(float), stream);
    hipMemsetAsync(cnt, 0, NN * sizeof(int), stream);

    hist_k<<<(NE + 255) / 256, 256, 0, stream>>>(dst, cnt);
    scan_part_k<<<SCAN_NB, 256, 0, stream>>>(cnt, bsum);
    scan_mid_k<<<1, 128, 0, stream>>>(bsum, boff, dstoff, gids, gcnt);
    scan_final_k<<<SCAN_NB, 256, 0, stream>>>(cnt, boff, dstoff, cur);
    prep_k<<<(NE + 255) / 256, 256, 0, stream>>>(src, dst, cemb, cur, src_d, dnorm_d,
                                                 feature, h16, W[0], W[1], W[2], Wt16,
                                                 statsAll);

    const float* h_old = feature;
    float* bufs[2] = {bufX, bufY};
    for (int l = 0; l < 3; l++) {
        float* agg    = bufs[l & 1];
        float* sumsN  = statsAll + (size_t)l * STATS_F;
        float* sumsqN = sumsN + NSL * 64;
        float* XgN    = sumsqN + NSL * 64;

        edge_gemm_k<<<(NN + 15) / 16, 256, 0, stream>>>(src_d, dstoff, dnorm_d, h16,
                                                        Wt16 + (size_t)l * 64 * 512,
                                                        gids, agg, sumsN, sumsqN, XgN);
        if (l < 2) {
            bn_apply_k<<<1024, 256, 0, stream>>>(agg, h_old, sumsN, sumsqN, gam[l], bet[l],
                                                 agg, h16, l > 0, XgN, gcnt, Pold,
                                                 cW1, cb1, cg1, cbt1, cW2, cb2, out);
        } else {
            classifier_only_k<<<1, 256, 0, stream>>>(sumsN, sumsqN, XgN, gcnt, Pold,
                                                     gam[l], bet[l],
                                                     cW1, cb1, cg1, cbt1, cW2, cb2, out);
        }
        h_old = agg;
    }
}